// Round 1
// 1806.908 us; speedup vs baseline: 1.1164x; 1.1164x over previous
//
#include <hip/hip_runtime.h>

#define SQRTD 11.313708498984761f

// ---------------------------------------------------------------- k_G
// G[h,e,o]  = sum_d Wsel_nb [h,d,e] * Wk_nb [h,d,o]   (2*256*64)
// G2[h,e,p] = sum_d Wsel_poi[h,d,e] * Wk_poi[h,d,p]   (2*256*32)
__global__ void k_G(const float* __restrict__ Wsel_nb, const float* __restrict__ Wk_nb,
                    const float* __restrict__ Wsel_poi, const float* __restrict__ Wk_poi,
                    float* __restrict__ G, float* __restrict__ G2) {
    int g = blockIdx.x * 256 + threadIdx.x;
    if (g < 32768) {
        int h = g >> 14, rem = g & 16383, e = rem >> 6, o = rem & 63;
        float s = 0.f;
        for (int d = 0; d < 128; d++)
            s += Wsel_nb[(h*128 + d)*256 + e] * Wk_nb[(h*128 + d)*64 + o];
        G[g] = s;
    } else if (g < 49152) {
        int q = g - 32768;
        int h = q >> 13, rem = q & 8191, e = rem >> 5, p = rem & 31;
        float s = 0.f;
        for (int d = 0; d < 128; d++)
            s += Wsel_poi[(h*128 + d)*256 + e] * Wk_poi[(h*128 + d)*32 + p];
        G2[q] = s;
    }
}

// ---------------------------------------------------------------- k_enc
// enc[row,j] = leaky_relu(b_enc[j] + sum_o obs[row, 448+o] * W_enc[j,o])
// No LDS: W_enc row lives in 16 float4 VGPRs per thread (j = t); the self
// row is wave-uniform -> s_load float4 + fma-with-SGPR (k_stage1 pattern).
// Accumulation order o = 0..63 sequential, identical to the LDS version.
// block=256, 32 rows/block, grid=1024
__global__ __launch_bounds__(256, 2) void k_enc(
        const float* __restrict__ obs, const float* __restrict__ W_enc,
        const float* __restrict__ b_enc, float* __restrict__ enc) {
    int t = threadIdx.x;
    int rowbase = blockIdx.x * 32;   // row = a*4096+b
    float4 w4[16];
    const float4* wrow = (const float4*)(W_enc + t*64);
    #pragma unroll
    for (int q = 0; q < 16; q++) w4[q] = wrow[q];
    float be = b_enc[t];
    for (int r = 0; r < 32; r++) {
        const float4* s4 = (const float4*)(obs + (size_t)(rowbase + r)*2560 + 448);  // uniform
        float acc = be;
        #pragma unroll
        for (int q = 0; q < 16; q++) {
            float4 s = s4[q];
            acc = fmaf(s.x, w4[q].x, acc);
            acc = fmaf(s.y, w4[q].y, acc);
            acc = fmaf(s.z, w4[q].z, acc);
            acc = fmaf(s.w, w4[q].w, acc);
        }
        acc = acc >= 0.f ? acc : 0.01f * acc;
        enc[(size_t)(rowbase + r)*256 + t] = acc;
    }
}

// ---------------------------------------------------------------- k_stage1
// T[row,o] = sum_e enc[row,e]*G[h,e,o]; logit[n] = dot(obs_nb[row,n,:], T)/sqrt(D)
// Wave w holds G[h, w*64+j, lane] in 64 VGPRs; enc comes in via wave-uniform
// scalar loads (readfirstlane'd base -> s_load + fma-with-SGPR). No LDS in
// the inner loop; cross-wave e-chunk partials combine through T_s.
// block=256 (4 waves), 32 rows/block, grid = 16 ha * 128 tiles
__global__ __launch_bounds__(256, 2) void k_stage1(
        const float* __restrict__ obs, const float* __restrict__ enc,
        const float* __restrict__ G, float* __restrict__ logit_raw,
        double* __restrict__ part1) {
    __shared__ float T_s[4][32][64];     // 32 KB
    __shared__ double dsum[4];
    int blk = blockIdx.x;
    int ha = blk >> 7, tile = blk & 127;
    int h = ha >> 3, a = ha & 7;
    int t = threadIdx.x, lane = t & 63;
    int wu = __builtin_amdgcn_readfirstlane(t >> 6);   // wave id, provably uniform
    int rowb = a*4096 + tile*32;

    // G chunk for this wave: e = wu*64 + j, o = lane
    float Greg[64];
    const float* gbase = G + h*16384 + wu*64*64 + lane;
    #pragma unroll
    for (int j = 0; j < 64; j++) Greg[j] = gbase[j*64];

    // phase 1: partial T over this wave's e-chunk, all 32 rows
    for (int r = 0; r < 32; r++) {
        const float* er = enc + (size_t)(rowb + r)*256 + wu*64;   // uniform base
        float acc = 0.f;
        #pragma unroll
        for (int q = 0; q < 16; q++) {
            float4 e4 = *(const float4*)(er + 4*q);   // s_load_dwordx4 expected
            acc = fmaf(e4.x, Greg[4*q+0], acc);
            acc = fmaf(e4.y, Greg[4*q+1], acc);
            acc = fmaf(e4.z, Greg[4*q+2], acc);
            acc = fmaf(e4.w, Greg[4*q+3], acc);
        }
        T_s[wu][r][lane] = acc;
    }
    __syncthreads();

    // phase 2: each wave finishes 8 rows: combine partials + logits
    double lsum = 0.0;
    for (int rr = 0; rr < 8; rr++) {
        int r = wu*8 + rr;
        int row = rowb + r;
        float T = (T_s[0][r][lane] + T_s[1][r][lane])
                + (T_s[2][r][lane] + T_s[3][r][lane]);
        #pragma unroll
        for (int n = 0; n < 7; n++) {
            float v = obs[(size_t)row*2560 + n*64 + lane] * T;
            #pragma unroll
            for (int mm = 32; mm >= 1; mm >>= 1) v += __shfl_xor(v, mm, 64);
            v = v / SQRTD;
            if (lane == 0) {
                logit_raw[(size_t)(ha*4096 + tile*32 + r)*7 + n] = v;
                lsum += (double)v;
            }
        }
    }
    if (lane == 0) dsum[wu] = lsum;
    __syncthreads();
    if (t == 0) part1[ha*128 + tile] = (dsum[0] + dsum[1]) + (dsum[2] + dsum[3]);
}

// ---------------------------------------------------------------- k_meanred
// deterministic tree reduction of 128 block partials -> mean scalar per (h,a)
__global__ void k_meanred(const double* __restrict__ partials, float* __restrict__ mean_out,
                          int denomN) {
    __shared__ double sd[128];
    int ha = blockIdx.x, t = threadIdx.x;
    sd[t] = partials[ha*128 + t];
    __syncthreads();
    for (int s = 64; s >= 1; s >>= 1) {
        if (t < s) sd[t] += sd[t + s];
        __syncthreads();
    }
    if (t == 0) mean_out[ha] = (float)(sd[0] / (double)denomN);
}

// ---------------------------------------------------------------- k_nbvals
// w = softmax_n(logit/denom); V = leaky(nb@Wv^T + bv); nb_all[.., h*128+d] = sum_n w*V
// No LDS / no barriers: the nb row (448 floats) is wave-uniform, so it comes
// in via scalar loads (s_load float4) and feeds fma-with-SGPR against the
// per-thread Wv row held in 16 float4 VGPRs. Arithmetic sequence identical
// to the previous LDS-broadcast version (bit-exact results).
// block=256 = (h,d); 32 rows/block, grid = 8 a * 128 tiles
__global__ __launch_bounds__(256, 2) void k_nbvals(
        const float* __restrict__ obs, const float* __restrict__ Wv_nb,
        const float* __restrict__ bv_nb, const float* __restrict__ logit_raw,
        const float* __restrict__ mean1, float* __restrict__ nb_all) {
    int blk = blockIdx.x;
    int a = blk >> 7, tile = blk & 127;
    int t = threadIdx.x;
    int h = __builtin_amdgcn_readfirstlane(t >> 7);   // wave-uniform
    int d = t & 127;
    float4 wv4[16];
    const float4* wrow = (const float4*)(Wv_nb + (h*128 + d)*64);
    #pragma unroll
    for (int oq = 0; oq < 16; oq++) wv4[oq] = wrow[oq];
    float bv = bv_nb[h*128 + d];
    float denom = mean1[h*8 + a] + 1e-9f;
    int b0 = tile*32;
    for (int rr = 0; rr < 32; rr++) {
        int b = b0 + rr;
        const float* nbrow = obs + (size_t)(a*4096 + b)*2560;           // uniform base
        const float* lr = logit_raw + ((size_t)((h*8 + a)*4096 + b))*7; // uniform base
        float L[7], va[7];
        float m = -3.4e38f;
        #pragma unroll
        for (int n = 0; n < 7; n++) { L[n] = lr[n] / denom; m = fmaxf(m, L[n]); }
        float s = 0.f;
        #pragma unroll
        for (int n = 0; n < 7; n++) { L[n] = expf(L[n] - m); s += L[n]; }
        #pragma unroll
        for (int n = 0; n < 7; n++) {
            const float4* nb4 = (const float4*)(nbrow + n*64);          // uniform
            float4 acc4 = {0.f, 0.f, 0.f, 0.f};
            #pragma unroll
            for (int oq = 0; oq < 16; oq++) {
                float4 nb = nb4[oq];
                acc4.x = fmaf(nb.x, wv4[oq].x, acc4.x);
                acc4.y = fmaf(nb.y, wv4[oq].y, acc4.y);
                acc4.z = fmaf(nb.z, wv4[oq].z, acc4.z);
                acc4.w = fmaf(nb.w, wv4[oq].w, acc4.w);
            }
            float v = bv + ((acc4.x + acc4.y) + (acc4.z + acc4.w));
            va[n] = v >= 0.f ? v : 0.01f * v;
        }
        float acc = 0.f;
        #pragma unroll
        for (int n = 0; n < 7; n++) acc += (L[n] / s) * va[n];
        nb_all[((size_t)(a*4096 + b))*256 + h*128 + d] = acc;
    }
}

// ---------------------------------------------------------------- k_stage2
// Tp[row,p] = sum_e nb_all[row,e]*G2[h,e,p]; lp[c] = dot(poi[c,b,:], Tp)/sqrt(D)
// Wave w holds G2[h, w*64+j, p] in 64 VGPRs (dup across halves). Lane=(sub,p):
// sub picks one of 2 rows per pair -> per-j loads hit 2 addresses, broadcast 32.
// block=256 (4 waves), 32 rows/block, grid = 16 ha * 128 tiles
__global__ __launch_bounds__(256, 2) void k_stage2(
        const float* __restrict__ obs, const float* __restrict__ nb_all,
        const float* __restrict__ G2, float* __restrict__ lp_raw,
        double* __restrict__ part2) {
    __shared__ float T_s[4][32][32];     // 16 KB
    __shared__ double dsum[4];
    int blk = blockIdx.x;
    int ha = blk >> 7, tile = blk & 127;
    int h = ha >> 3, a = ha & 7;
    int t = threadIdx.x, lane = t & 63;
    int sub = (lane >> 5), p = lane & 31;
    int wu = __builtin_amdgcn_readfirstlane(t >> 6);
    int rowb = a*4096 + tile*32;

    float Greg[64];
    const float* gbase = G2 + h*8192 + wu*64*32 + p;
    #pragma unroll
    for (int j = 0; j < 64; j++) Greg[j] = gbase[j*32];

    // phase 1: 16 row-pairs; lane's row = pair*2 + sub
    for (int rp = 0; rp < 16; rp++) {
        int r = rp*2 + sub;
        const float* nr = nb_all + (size_t)(rowb + r)*256 + wu*64;
        float acc = 0.f;
        #pragma unroll
        for (int q = 0; q < 16; q++) {
            float4 e4 = *(const float4*)(nr + 4*q);
            acc = fmaf(e4.x, Greg[4*q+0], acc);
            acc = fmaf(e4.y, Greg[4*q+1], acc);
            acc = fmaf(e4.z, Greg[4*q+2], acc);
            acc = fmaf(e4.w, Greg[4*q+3], acc);
        }
        T_s[wu][r][p] = acc;
    }
    __syncthreads();

    // phase 2: each wave finishes 8 rows; 2 c's per iteration (sub = c parity)
    double lsum = 0.0;
    for (int rr = 0; rr < 8; rr++) {
        int r = wu*8 + rr;
        int b = tile*32 + r;
        float Tp = (T_s[0][r][p] + T_s[1][r][p]) + (T_s[2][r][p] + T_s[3][r][p]);
        size_t pbase = (size_t)b*2560 + 512;   // poi lives in agent-0 rows
        for (int cb = 0; cb < 32; cb++) {
            int c = cb*2 + sub;
            float v = obs[pbase + cb*64 + lane] * Tp;   // coalesced 64 floats
            #pragma unroll
            for (int mm = 16; mm >= 1; mm >>= 1) v += __shfl_xor(v, mm, 32);
            v = v / SQRTD;
            if (p == 0) {
                lp_raw[(size_t)(ha*4096 + b)*64 + c] = v;
                lsum += (double)v;
            }
        }
    }
    // lanes 0 and 32 hold partial sums; combine then store per-wave
    lsum += __shfl_xor(lsum, 32, 64);
    if (lane == 0) dsum[wu] = lsum;
    __syncthreads();
    if (t == 0) part2[ha*128 + tile] = (dsum[0] + dsum[1]) + (dsum[2] + dsum[3]);
}

// ---------------------------------------------------------------- k_colmax_part
// per (ha, chunk of 256 b): softmax rows over c, track per-column (max w, min b)
// block=256 = 4 waves; lane c = t&63; grid = 16*16
__global__ void k_colmax_part(const float* __restrict__ lp_raw, const float* __restrict__ mean2,
                              float* __restrict__ colv_p, int* __restrict__ colb_p) {
    int blk = blockIdx.x;
    int ha = blk >> 4, chunk = blk & 15;
    int t = threadIdx.x, c = t & 63, wv = t >> 6;
    float denom = mean2[ha] + 1e-9f;
    float bestv = -1e30f; int bestb = 1 << 30;
    for (int k = 0; k < 64; k++) {
        int b = chunk*256 + wv + 4*k;
        float x = lp_raw[(size_t)(ha*4096 + b)*64 + c] / denom;
        float m = x;
        #pragma unroll
        for (int mm = 32; mm >= 1; mm >>= 1) m = fmaxf(m, __shfl_xor(m, mm, 64));
        float e = expf(x - m);
        float s = e;
        #pragma unroll
        for (int mm = 32; mm >= 1; mm >>= 1) s += __shfl_xor(s, mm, 64);
        float w = e / s;
        if (w > bestv) { bestv = w; bestb = b; }   // strict > keeps earliest b per thread
    }
    __shared__ float sv[4][64];
    __shared__ int   sb[4][64];
    sv[wv][c] = bestv; sb[wv][c] = bestb;
    __syncthreads();
    if (t < 64) {
        float v = sv[0][t]; int bb = sb[0][t];
        for (int j = 1; j < 4; j++) {
            float vj = sv[j][t]; int bj = sb[j][t];
            if (vj > v || (vj == v && bj < bb)) { v = vj; bb = bj; }
        }
        colv_p[(ha*16 + chunk)*64 + t] = v;
        colb_p[(ha*16 + chunk)*64 + t] = bb;
    }
}

// ---------------------------------------------------------------- k_colmerge
__global__ void k_colmerge(const float* __restrict__ colv_p, const int* __restrict__ colb_p,
                           float* __restrict__ colv, int* __restrict__ colb) {
    int ha = blockIdx.x, c = threadIdx.x;   // 64 threads
    float v = colv_p[(ha*16)*64 + c]; int bb = colb_p[(ha*16)*64 + c];
    for (int j = 1; j < 16; j++) {
        float vj = colv_p[(ha*16 + j)*64 + c]; int bj = colb_p[(ha*16 + j)*64 + c];
        if (vj > v || (vj == v && bj < bb)) { v = vj; bb = bj; }
    }
    colv[ha*64 + c] = v; colb[ha*64 + c] = bb;
}

// ---------------------------------------------------------------- k_scan
// 16-step sequential argmax scan, parallel over 64 lanes (one column each).
// Exact jnp.argmax first-occurrence semantics: masked column c contributes
// (0.0, flat=c); winner tie-break is (v desc, flat asc) via butterfly.
__global__ void k_scan(const float* __restrict__ obs, const float* __restrict__ colv,
                       const int* __restrict__ colb, float* __restrict__ out) {
    __shared__ float cif_s[8];
    int t = threadIdx.x;
    if (t < 64) {
        int c = t;
        int idx = (32*c + 2047) & 2047;          // (32c - 1) mod 2048
        float ifc = obs[512 + idx];              // agent 0, batch 0 cargo features
        float cv[16]; int cb[16];
        #pragma unroll
        for (int i = 0; i < 16; i++) { cv[i] = colv[i*64 + c]; cb[i] = colb[i*64 + c]; }
        float cif[8];
        for (int i = 0; i < 16; i++) {
            float v; int flat;
            if (ifc == 1.0f) { v = 0.0f; flat = c; }
            else { v = cv[i]; flat = cb[i]*64 + c; }
            #pragma unroll
            for (int mm = 32; mm >= 1; mm >>= 1) {
                float vo = __shfl_xor(v, mm, 64);
                int fo = __shfl_xor(flat, mm, 64);
                if (vo > v || (vo == v && fo < flat)) { v = vo; flat = fo; }
            }
            if (flat < 64 && c == flat) ifc = 1.0f;  // OOB scatter dropped, like JAX
            cif[i & 7] = (float)flat;                // agent = i % 8; later steps overwrite
        }
        if (t == 0) {
            #pragma unroll
            for (int a = 0; a < 8; a++) cif_s[a] = cif[a];
        }
    }
    __syncthreads();
    for (int a = 0; a < 8; a++)
        for (int k = t; k < 4096; k += 256)
            out[a*4096 + k] = cif_s[a];
}

// ---------------------------------------------------------------- launch
extern "C" void kernel_launch(void* const* d_in, const int* in_sizes, int n_in,
                              void* d_out, int out_size, void* d_ws, size_t ws_size,
                              hipStream_t stream) {
    const float* obs      = (const float*)d_in[0];
    const float* W_enc    = (const float*)d_in[1];
    const float* b_enc    = (const float*)d_in[2];
    const float* Wk_nb    = (const float*)d_in[3];
    const float* Wsel_nb  = (const float*)d_in[4];
    const float* Wv_nb    = (const float*)d_in[5];
    const float* bv_nb    = (const float*)d_in[6];
    const float* Wk_poi   = (const float*)d_in[7];
    const float* Wsel_poi = (const float*)d_in[8];
    // d_in[9] Wv_poi, d_in[10] bv_poi: unused by the reference output
    float* out = (float*)d_out;

    char* ws = (char*)d_ws;
    float*  enc       = (float*) (ws + 0);          // 33554432 B
    float*  nb_all    = (float*) (ws + 33554432);   // 33554432 B
    float*  lp_raw    = (float*) (ws + 67108864);   // 16777216 B
    float*  logit_raw = (float*) (ws + 83886080);   // 1835008 B
    float*  G         = (float*) (ws + 85721088);   // 131072 B
    float*  G2        = (float*) (ws + 85852160);   // 65536 B
    double* part1     = (double*)(ws + 85917696);   // 16384 B
    double* part2     = (double*)(ws + 85934080);   // 16384 B
    float*  mean1     = (float*) (ws + 85950464);   // 64 B
    float*  mean2     = (float*) (ws + 85950528);   // 64 B
    float*  colv_p    = (float*) (ws + 85950592);   // 65536 B
    int*    colb_p    = (int*)   (ws + 86016128);   // 65536 B
    float*  colv      = (float*) (ws + 86081664);   // 4096 B
    int*    colb      = (int*)   (ws + 86085760);   // 4096 B

    hipLaunchKernelGGL(k_G,           dim3(192),  dim3(256), 0, stream,
                       Wsel_nb, Wk_nb, Wsel_poi, Wk_poi, G, G2);
    hipLaunchKernelGGL(k_enc,         dim3(1024), dim3(256), 0, stream,
                       obs, W_enc, b_enc, enc);
    hipLaunchKernelGGL(k_stage1,      dim3(2048), dim3(256), 0, stream,
                       obs, enc, G, logit_raw, part1);
    hipLaunchKernelGGL(k_meanred,     dim3(16),   dim3(128), 0, stream,
                       part1, mean1, 28672);
    hipLaunchKernelGGL(k_nbvals,      dim3(1024), dim3(256), 0, stream,
                       obs, Wv_nb, bv_nb, logit_raw, mean1, nb_all);
    hipLaunchKernelGGL(k_stage2,      dim3(2048), dim3(256), 0, stream,
                       obs, nb_all, G2, lp_raw, part2);
    hipLaunchKernelGGL(k_meanred,     dim3(16),   dim3(128), 0, stream,
                       part2, mean2, 262144);
    hipLaunchKernelGGL(k_colmax_part, dim3(256),  dim3(256), 0, stream,
                       lp_raw, mean2, colv_p, colb_p);
    hipLaunchKernelGGL(k_colmerge,    dim3(16),   dim3(64),  0, stream,
                       colv_p, colb_p, colv, colb);
    hipLaunchKernelGGL(k_scan,        dim3(1),    dim3(256), 0, stream,
                       obs, colv, colb, out);
}

// Round 2
// 1518.988 us; speedup vs baseline: 1.3280x; 1.1895x over previous
//
#include <hip/hip_runtime.h>

#define SQRTD 11.313708498984761f

// ---------------------------------------------------------------- k_G
// G[h,e,o]  = sum_d Wsel_nb [h,d,e] * Wk_nb [h,d,o]   (2*256*64)
// G2[h,e,p] = sum_d Wsel_poi[h,d,e] * Wk_poi[h,d,p]   (2*256*32)
__global__ void k_G(const float* __restrict__ Wsel_nb, const float* __restrict__ Wk_nb,
                    const float* __restrict__ Wsel_poi, const float* __restrict__ Wk_poi,
                    float* __restrict__ G, float* __restrict__ G2) {
    int g = blockIdx.x * 256 + threadIdx.x;
    if (g < 32768) {
        int h = g >> 14, rem = g & 16383, e = rem >> 6, o = rem & 63;
        float s = 0.f;
        for (int d = 0; d < 128; d++)
            s += Wsel_nb[(h*128 + d)*256 + e] * Wk_nb[(h*128 + d)*64 + o];
        G[g] = s;
    } else if (g < 49152) {
        int q = g - 32768;
        int h = q >> 13, rem = q & 8191, e = rem >> 5, p = rem & 31;
        float s = 0.f;
        for (int d = 0; d < 128; d++)
            s += Wsel_poi[(h*128 + d)*256 + e] * Wk_poi[(h*128 + d)*32 + p];
        G2[q] = s;
    }
}

// ---------------------------------------------------------------- k_enc
// enc[row,j] = leaky_relu(b_enc[j] + sum_o obs[row, 448+o] * W_enc[j,o])
// No LDS: W_enc row lives in 16 float4 VGPRs per thread (j = t); the self
// row is wave-uniform -> s_load float4 + fma-with-SGPR (k_stage1 pattern).
// block=256, 32 rows/block, grid=1024
__global__ __launch_bounds__(256, 2) void k_enc(
        const float* __restrict__ obs, const float* __restrict__ W_enc,
        const float* __restrict__ b_enc, float* __restrict__ enc) {
    int t = threadIdx.x;
    int rowbase = blockIdx.x * 32;   // row = a*4096+b
    float4 w4[16];
    const float4* wrow = (const float4*)(W_enc + t*64);
    #pragma unroll
    for (int q = 0; q < 16; q++) w4[q] = wrow[q];
    float be = b_enc[t];
    for (int r = 0; r < 32; r++) {
        const float4* s4 = (const float4*)(obs + (size_t)(rowbase + r)*2560 + 448);  // uniform
        float acc = be;
        #pragma unroll
        for (int q = 0; q < 16; q++) {
            float4 s = s4[q];
            acc = fmaf(s.x, w4[q].x, acc);
            acc = fmaf(s.y, w4[q].y, acc);
            acc = fmaf(s.z, w4[q].z, acc);
            acc = fmaf(s.w, w4[q].w, acc);
        }
        acc = acc >= 0.f ? acc : 0.01f * acc;
        enc[(size_t)(rowbase + r)*256 + t] = acc;
    }
}

// ---------------------------------------------------------------- k_stage1
// T[row,o] = sum_e enc[row,e]*G[h,e,o]; logit[n] = dot(obs_nb[row,n,:], T)/sqrt(D)
// Arithmetic unchanged (bit-identical); launch_bounds 2->4 blocks/CU for
// latency hiding (VGPR 92 fits the 128 cap; LDS 32.8KB x4 fits 160KB).
// block=256 (4 waves), 32 rows/block, grid = 16 ha * 128 tiles
__global__ __launch_bounds__(256, 4) void k_stage1(
        const float* __restrict__ obs, const float* __restrict__ enc,
        const float* __restrict__ G, float* __restrict__ logit_raw,
        double* __restrict__ part1) {
    __shared__ float T_s[4][32][64];     // 32 KB
    __shared__ double dsum[4];
    int blk = blockIdx.x;
    int ha = blk >> 7, tile = blk & 127;
    int h = ha >> 3, a = ha & 7;
    int t = threadIdx.x, lane = t & 63;
    int wu = __builtin_amdgcn_readfirstlane(t >> 6);   // wave id, provably uniform
    int rowb = a*4096 + tile*32;

    // G chunk for this wave: e = wu*64 + j, o = lane
    float Greg[64];
    const float* gbase = G + h*16384 + wu*64*64 + lane;
    #pragma unroll
    for (int j = 0; j < 64; j++) Greg[j] = gbase[j*64];

    // phase 1: partial T over this wave's e-chunk, all 32 rows
    for (int r = 0; r < 32; r++) {
        const float* er = enc + (size_t)(rowb + r)*256 + wu*64;   // uniform base
        float acc = 0.f;
        #pragma unroll
        for (int q = 0; q < 16; q++) {
            float4 e4 = *(const float4*)(er + 4*q);   // s_load_dwordx4 expected
            acc = fmaf(e4.x, Greg[4*q+0], acc);
            acc = fmaf(e4.y, Greg[4*q+1], acc);
            acc = fmaf(e4.z, Greg[4*q+2], acc);
            acc = fmaf(e4.w, Greg[4*q+3], acc);
        }
        T_s[wu][r][lane] = acc;
    }
    __syncthreads();

    // phase 2: each wave finishes 8 rows: combine partials + logits
    double lsum = 0.0;
    for (int rr = 0; rr < 8; rr++) {
        int r = wu*8 + rr;
        int row = rowb + r;
        float T = (T_s[0][r][lane] + T_s[1][r][lane])
                + (T_s[2][r][lane] + T_s[3][r][lane]);
        #pragma unroll
        for (int n = 0; n < 7; n++) {
            float v = obs[(size_t)row*2560 + n*64 + lane] * T;
            #pragma unroll
            for (int mm = 32; mm >= 1; mm >>= 1) v += __shfl_xor(v, mm, 64);
            v = v / SQRTD;
            if (lane == 0) {
                logit_raw[(size_t)(ha*4096 + tile*32 + r)*7 + n] = v;
                lsum += (double)v;
            }
        }
    }
    if (lane == 0) dsum[wu] = lsum;
    __syncthreads();
    if (t == 0) part1[ha*128 + tile] = (dsum[0] + dsum[1]) + (dsum[2] + dsum[3]);
}

// ---------------------------------------------------------------- k_meanred
// deterministic tree reduction of 128 block partials -> mean scalar per (h,a)
__global__ void k_meanred(const double* __restrict__ partials, float* __restrict__ mean_out,
                          int denomN) {
    __shared__ double sd[128];
    int ha = blockIdx.x, t = threadIdx.x;
    sd[t] = partials[ha*128 + t];
    __syncthreads();
    for (int s = 64; s >= 1; s >>= 1) {
        if (t < s) sd[t] += sd[t + s];
        __syncthreads();
    }
    if (t == 0) mean_out[ha] = (float)(sd[0] / (double)denomN);
}

// ---------------------------------------------------------------- k_nbvals
// w = softmax_n(logit/denom); V = leaky(nb@Wv^T + bv); nb_all[.., h*128+d] = sum_n w*V
// No LDS / no barriers: nb row is wave-uniform -> scalar loads + fma-with-SGPR
// against the per-thread Wv row in 16 float4 VGPRs. Bit-exact vs LDS version.
// block=256 = (h,d); 32 rows/block, grid = 8 a * 128 tiles
__global__ __launch_bounds__(256, 2) void k_nbvals(
        const float* __restrict__ obs, const float* __restrict__ Wv_nb,
        const float* __restrict__ bv_nb, const float* __restrict__ logit_raw,
        const float* __restrict__ mean1, float* __restrict__ nb_all) {
    int blk = blockIdx.x;
    int a = blk >> 7, tile = blk & 127;
    int t = threadIdx.x;
    int h = __builtin_amdgcn_readfirstlane(t >> 7);   // wave-uniform
    int d = t & 127;
    float4 wv4[16];
    const float4* wrow = (const float4*)(Wv_nb + (h*128 + d)*64);
    #pragma unroll
    for (int oq = 0; oq < 16; oq++) wv4[oq] = wrow[oq];
    float bv = bv_nb[h*128 + d];
    float denom = mean1[h*8 + a] + 1e-9f;
    int b0 = tile*32;
    for (int rr = 0; rr < 32; rr++) {
        int b = b0 + rr;
        const float* nbrow = obs + (size_t)(a*4096 + b)*2560;           // uniform base
        const float* lr = logit_raw + ((size_t)((h*8 + a)*4096 + b))*7; // uniform base
        float L[7], va[7];
        float m = -3.4e38f;
        #pragma unroll
        for (int n = 0; n < 7; n++) { L[n] = lr[n] / denom; m = fmaxf(m, L[n]); }
        float s = 0.f;
        #pragma unroll
        for (int n = 0; n < 7; n++) { L[n] = expf(L[n] - m); s += L[n]; }
        #pragma unroll
        for (int n = 0; n < 7; n++) {
            const float4* nb4 = (const float4*)(nbrow + n*64);          // uniform
            float4 acc4 = {0.f, 0.f, 0.f, 0.f};
            #pragma unroll
            for (int oq = 0; oq < 16; oq++) {
                float4 nb = nb4[oq];
                acc4.x = fmaf(nb.x, wv4[oq].x, acc4.x);
                acc4.y = fmaf(nb.y, wv4[oq].y, acc4.y);
                acc4.z = fmaf(nb.z, wv4[oq].z, acc4.z);
                acc4.w = fmaf(nb.w, wv4[oq].w, acc4.w);
            }
            float v = bv + ((acc4.x + acc4.y) + (acc4.z + acc4.w));
            va[n] = v >= 0.f ? v : 0.01f * v;
        }
        float acc = 0.f;
        #pragma unroll
        for (int n = 0; n < 7; n++) acc += (L[n] / s) * va[n];
        nb_all[((size_t)(a*4096 + b))*256 + h*128 + d] = acc;
    }
}

// ---------------------------------------------------------------- k_stage2
// Tp[row,p] = sum_e nb_all[row,e]*G2[h,e,p]; lp[c] = dot(poi[c,b,:], Tp)/sqrt(D)
// Phase 1 unchanged (bitwise-identical Tp partials in T_s).
// Phase 2 rewritten: lane c owns column c for the wave's 8 rows. Full Tp row
// comes in via LDS broadcast reads; lane's poi slice is exactly one 128B line
// (8 dwordx4, L1-resident). The dot is computed in-register with __fmul_rn
// products and an add tree that replicates the old shfl_xor(16,8,4,2,1)
// association bit-exactly -> lp_raw is bitwise unchanged. lp store is now a
// fully-coalesced 256B write; the per-iteration 5-deep shuffle chains and
// 64-lane divides are gone (12 shuffles + 8 divides per lane total).
// part2 order changes only in double accumulation (~1e-13, benign).
// block=256 (4 waves), 32 rows/block, grid = 16 ha * 128 tiles
__global__ __launch_bounds__(256, 4) void k_stage2(
        const float* __restrict__ obs, const float* __restrict__ nb_all,
        const float* __restrict__ G2, float* __restrict__ lp_raw,
        double* __restrict__ part2) {
    __shared__ float T_s[4][32][32];     // 16 KB
    __shared__ double dsum[4];
    int blk = blockIdx.x;
    int ha = blk >> 7, tile = blk & 127;
    int h = ha >> 3, a = ha & 7;
    int t = threadIdx.x, lane = t & 63;
    int sub = (lane >> 5), p = lane & 31;
    int wu = __builtin_amdgcn_readfirstlane(t >> 6);
    int rowb = a*4096 + tile*32;

    float Greg[64];
    const float* gbase = G2 + h*8192 + wu*64*32 + p;
    #pragma unroll
    for (int j = 0; j < 64; j++) Greg[j] = gbase[j*32];

    // phase 1: 16 row-pairs; lane's row = pair*2 + sub  (unchanged)
    for (int rp = 0; rp < 16; rp++) {
        int r = rp*2 + sub;
        const float* nr = nb_all + (size_t)(rowb + r)*256 + wu*64;
        float acc = 0.f;
        #pragma unroll
        for (int q = 0; q < 16; q++) {
            float4 e4 = *(const float4*)(nr + 4*q);
            acc = fmaf(e4.x, Greg[4*q+0], acc);
            acc = fmaf(e4.y, Greg[4*q+1], acc);
            acc = fmaf(e4.z, Greg[4*q+2], acc);
            acc = fmaf(e4.w, Greg[4*q+3], acc);
        }
        T_s[wu][r][p] = acc;
    }
    __syncthreads();

    // phase 2: each wave finishes 8 rows; lane c computes column c entirely
    double lsum = 0.0;
    for (int rr = 0; rr < 8; rr++) {
        int r = wu*8 + rr;
        int b = tile*32 + r;
        // full Tp row via LDS broadcast (same combine expression as before)
        float tp[32];
        #pragma unroll
        for (int q = 0; q < 8; q++) {
            float4 t0 = *(const float4*)&T_s[0][r][4*q];
            float4 t1 = *(const float4*)&T_s[1][r][4*q];
            float4 t2 = *(const float4*)&T_s[2][r][4*q];
            float4 t3 = *(const float4*)&T_s[3][r][4*q];
            tp[4*q+0] = (t0.x + t1.x) + (t2.x + t3.x);
            tp[4*q+1] = (t0.y + t1.y) + (t2.y + t3.y);
            tp[4*q+2] = (t0.z + t1.z) + (t2.z + t3.z);
            tp[4*q+3] = (t0.w + t1.w) + (t2.w + t3.w);
        }
        // lane's poi slice: one 128B line
        const float4* pf4 = (const float4*)(obs + (size_t)b*2560 + 512 + lane*32);
        float m[32];
        #pragma unroll
        for (int q = 0; q < 8; q++) {
            float4 pv = pf4[q];
            m[4*q+0] = __fmul_rn(pv.x, tp[4*q+0]);
            m[4*q+1] = __fmul_rn(pv.y, tp[4*q+1]);
            m[4*q+2] = __fmul_rn(pv.z, tp[4*q+2]);
            m[4*q+3] = __fmul_rn(pv.w, tp[4*q+3]);
        }
        // add tree == old shfl_xor(16,8,4,2,1) association, bit-exact
        float A[16], Bv[8], C[4], Dv[2];
        #pragma unroll
        for (int k = 0; k < 16; k++) A[k] = m[k] + m[k + 16];
        #pragma unroll
        for (int k = 0; k < 8; k++) Bv[k] = A[k] + A[k + 8];
        #pragma unroll
        for (int k = 0; k < 4; k++) C[k] = Bv[k] + Bv[k + 4];
        #pragma unroll
        for (int k = 0; k < 2; k++) Dv[k] = C[k] + C[k + 2];
        float v = (Dv[0] + Dv[1]) / SQRTD;
        lp_raw[(size_t)(ha*4096 + b)*64 + lane] = v;   // coalesced 256B store
        lsum += (double)v;
    }
    // deterministic butterfly over 64 lanes (double), then per-wave combine
    #pragma unroll
    for (int mm = 32; mm >= 1; mm >>= 1) lsum += __shfl_xor(lsum, mm, 64);
    if (lane == 0) dsum[wu] = lsum;
    __syncthreads();
    if (t == 0) part2[ha*128 + tile] = (dsum[0] + dsum[1]) + (dsum[2] + dsum[3]);
}

// ---------------------------------------------------------------- k_colmax_part
// per (ha, chunk of 256 b): softmax rows over c, track per-column (max w, min b)
// block=256 = 4 waves; lane c = t&63; grid = 16*16
__global__ void k_colmax_part(const float* __restrict__ lp_raw, const float* __restrict__ mean2,
                              float* __restrict__ colv_p, int* __restrict__ colb_p) {
    int blk = blockIdx.x;
    int ha = blk >> 4, chunk = blk & 15;
    int t = threadIdx.x, c = t & 63, wv = t >> 6;
    float denom = mean2[ha] + 1e-9f;
    float bestv = -1e30f; int bestb = 1 << 30;
    for (int k = 0; k < 64; k++) {
        int b = chunk*256 + wv + 4*k;
        float x = lp_raw[(size_t)(ha*4096 + b)*64 + c] / denom;
        float m = x;
        #pragma unroll
        for (int mm = 32; mm >= 1; mm >>= 1) m = fmaxf(m, __shfl_xor(m, mm, 64));
        float e = expf(x - m);
        float s = e;
        #pragma unroll
        for (int mm = 32; mm >= 1; mm >>= 1) s += __shfl_xor(s, mm, 64);
        float w = e / s;
        if (w > bestv) { bestv = w; bestb = b; }   // strict > keeps earliest b per thread
    }
    __shared__ float sv[4][64];
    __shared__ int   sb[4][64];
    sv[wv][c] = bestv; sb[wv][c] = bestb;
    __syncthreads();
    if (t < 64) {
        float v = sv[0][t]; int bb = sb[0][t];
        for (int j = 1; j < 4; j++) {
            float vj = sv[j][t]; int bj = sb[j][t];
            if (vj > v || (vj == v && bj < bb)) { v = vj; bb = bj; }
        }
        colv_p[(ha*16 + chunk)*64 + t] = v;
        colb_p[(ha*16 + chunk)*64 + t] = bb;
    }
}

// ---------------------------------------------------------------- k_colmerge
__global__ void k_colmerge(const float* __restrict__ colv_p, const int* __restrict__ colb_p,
                           float* __restrict__ colv, int* __restrict__ colb) {
    int ha = blockIdx.x, c = threadIdx.x;   // 64 threads
    float v = colv_p[(ha*16)*64 + c]; int bb = colb_p[(ha*16)*64 + c];
    for (int j = 1; j < 16; j++) {
        float vj = colv_p[(ha*16 + j)*64 + c]; int bj = colb_p[(ha*16 + j)*64 + c];
        if (vj > v || (vj == v && bj < bb)) { v = vj; bb = bj; }
    }
    colv[ha*64 + c] = v; colb[ha*64 + c] = bb;
}

// ---------------------------------------------------------------- k_scan
// 16-step sequential argmax scan, parallel over 64 lanes (one column each).
// Exact jnp.argmax first-occurrence semantics: masked column c contributes
// (0.0, flat=c); winner tie-break is (v desc, flat asc) via butterfly.
__global__ void k_scan(const float* __restrict__ obs, const float* __restrict__ colv,
                       const int* __restrict__ colb, float* __restrict__ out) {
    __shared__ float cif_s[8];
    int t = threadIdx.x;
    if (t < 64) {
        int c = t;
        int idx = (32*c + 2047) & 2047;          // (32c - 1) mod 2048
        float ifc = obs[512 + idx];              // agent 0, batch 0 cargo features
        float cv[16]; int cb[16];
        #pragma unroll
        for (int i = 0; i < 16; i++) { cv[i] = colv[i*64 + c]; cb[i] = colb[i*64 + c]; }
        float cif[8];
        for (int i = 0; i < 16; i++) {
            float v; int flat;
            if (ifc == 1.0f) { v = 0.0f; flat = c; }
            else { v = cv[i]; flat = cb[i]*64 + c; }
            #pragma unroll
            for (int mm = 32; mm >= 1; mm >>= 1) {
                float vo = __shfl_xor(v, mm, 64);
                int fo = __shfl_xor(flat, mm, 64);
                if (vo > v || (vo == v && fo < flat)) { v = vo; flat = fo; }
            }
            if (flat < 64 && c == flat) ifc = 1.0f;  // OOB scatter dropped, like JAX
            cif[i & 7] = (float)flat;                // agent = i % 8; later steps overwrite
        }
        if (t == 0) {
            #pragma unroll
            for (int a = 0; a < 8; a++) cif_s[a] = cif[a];
        }
    }
    __syncthreads();
    for (int a = 0; a < 8; a++)
        for (int k = t; k < 4096; k += 256)
            out[a*4096 + k] = cif_s[a];
}

// ---------------------------------------------------------------- launch
extern "C" void kernel_launch(void* const* d_in, const int* in_sizes, int n_in,
                              void* d_out, int out_size, void* d_ws, size_t ws_size,
                              hipStream_t stream) {
    const float* obs      = (const float*)d_in[0];
    const float* W_enc    = (const float*)d_in[1];
    const float* b_enc    = (const float*)d_in[2];
    const float* Wk_nb    = (const float*)d_in[3];
    const float* Wsel_nb  = (const float*)d_in[4];
    const float* Wv_nb    = (const float*)d_in[5];
    const float* bv_nb    = (const float*)d_in[6];
    const float* Wk_poi   = (const float*)d_in[7];
    const float* Wsel_poi = (const float*)d_in[8];
    // d_in[9] Wv_poi, d_in[10] bv_poi: unused by the reference output
    float* out = (float*)d_out;

    char* ws = (char*)d_ws;
    float*  enc       = (float*) (ws + 0);          // 33554432 B
    float*  nb_all    = (float*) (ws + 33554432);   // 33554432 B
    float*  lp_raw    = (float*) (ws + 67108864);   // 16777216 B
    float*  logit_raw = (float*) (ws + 83886080);   // 1835008 B
    float*  G         = (float*) (ws + 85721088);   // 131072 B
    float*  G2        = (float*) (ws + 85852160);   // 65536 B
    double* part1     = (double*)(ws + 85917696);   // 16384 B
    double* part2     = (double*)(ws + 85934080);   // 16384 B
    float*  mean1     = (float*) (ws + 85950464);   // 64 B
    float*  mean2     = (float*) (ws + 85950528);   // 64 B
    float*  colv_p    = (float*) (ws + 85950592);   // 65536 B
    int*    colb_p    = (int*)   (ws + 86016128);   // 65536 B
    float*  colv      = (float*) (ws + 86081664);   // 4096 B
    int*    colb      = (int*)   (ws + 86085760);   // 4096 B

    hipLaunchKernelGGL(k_G,           dim3(192),  dim3(256), 0, stream,
                       Wsel_nb, Wk_nb, Wsel_poi, Wk_poi, G, G2);
    hipLaunchKernelGGL(k_enc,         dim3(1024), dim3(256), 0, stream,
                       obs, W_enc, b_enc, enc);
    hipLaunchKernelGGL(k_stage1,      dim3(2048), dim3(256), 0, stream,
                       obs, enc, G, logit_raw, part1);
    hipLaunchKernelGGL(k_meanred,     dim3(16),   dim3(128), 0, stream,
                       part1, mean1, 28672);
    hipLaunchKernelGGL(k_nbvals,      dim3(1024), dim3(256), 0, stream,
                       obs, Wv_nb, bv_nb, logit_raw, mean1, nb_all);
    hipLaunchKernelGGL(k_stage2,      dim3(2048), dim3(256), 0, stream,
                       obs, nb_all, G2, lp_raw, part2);
    hipLaunchKernelGGL(k_meanred,     dim3(16),   dim3(128), 0, stream,
                       part2, mean2, 262144);
    hipLaunchKernelGGL(k_colmax_part, dim3(256),  dim3(256), 0, stream,
                       lp_raw, mean2, colv_p, colb_p);
    hipLaunchKernelGGL(k_colmerge,    dim3(16),   dim3(64),  0, stream,
                       colv_p, colb_p, colv, colb);
    hipLaunchKernelGGL(k_scan,        dim3(1),    dim3(256), 0, stream,
                       obs, colv, colb, out);
}